// Round 21
// baseline (48.233 us; speedup 1.0000x reference)
//
#include <hip/hip_runtime.h>
#include <hip/hip_bf16.h>

#define TSEQ 256
#define NBATCH 2
#define NAG 8
#define NH 8
#define HD 64
#define EE 512
#define WHALF 16
#define WW 33
#define WN 264   // WW*NAG

typedef __attribute__((ext_vector_type(8))) short short8;
typedef __attribute__((ext_vector_type(4))) short short4v;
typedef __attribute__((ext_vector_type(4))) float f32x4;
typedef _Float16 f16x8 __attribute__((ext_vector_type(8)));

static __device__ __forceinline__ unsigned short f2bf(float f) {
    unsigned int u = __float_as_uint(f);
    unsigned int r = (u + 0x7FFFu + ((u >> 16) & 1u)) >> 16;
    return (unsigned short)r;
}
static __device__ __forceinline__ unsigned int cvt_pk_bf16(float lo, float hi) {
    unsigned int r;
    asm("v_cvt_pk_bf16_f32 %0, %1, %2" : "=v"(r) : "v"(lo), "v"(hi));
    return r;
}
static __device__ __forceinline__ unsigned short f2h(float f) {
    _Float16 h = (_Float16)f;
    return __builtin_bit_cast(unsigned short, h);
}
static __device__ __forceinline__ float h2f(unsigned short u) {
    return (float)__builtin_bit_cast(_Float16, u);
}
static __device__ __forceinline__ f16x8 as_f16x8(short8 s) {
    return __builtin_bit_cast(f16x8, s);
}

// ---------------- fused QKV projection GEMM (bf16 MFMA) -----------------
// BM=64, BN=128, BK=64, 4 waves. 768 blocks. (unchanged)
__global__ __launch_bounds__(256)
void proj_mfma_kernel(const float* __restrict__ xq, const float* __restrict__ xk,
                      const float* __restrict__ xv,
                      const float* __restrict__ Wq, const float* __restrict__ Wk,
                      const float* __restrict__ Wv,
                      const float* __restrict__ bq, const float* __restrict__ bk,
                      const float* __restrict__ bv,
                      unsigned short* __restrict__ oq,
                      unsigned short* __restrict__ kswz,
                      unsigned short* __restrict__ vswz)
{
    __shared__ __align__(16) char LS[24576];
    char* As = LS;
    char* Bs = LS + 8192;

    const float* x; const float* W; const float* bias; float scale;
    const int z = blockIdx.z;
    if (z == 0)      { x = xq; W = Wq; bias = bq; scale = 0.125f; }
    else if (z == 1) { x = xk; W = Wk; bias = bk; scale = 1.0f; }
    else             { x = xv; W = Wv; bias = bv; scale = 1.0f; }

    const int tid  = threadIdx.x;
    const int lane = tid & 63;
    const int wid  = tid >> 6;
    const int i0 = blockIdx.x * 64;
    const int f0 = blockIdx.y * 128;
    const int wr = wid >> 1, wc = wid & 1;

    f32x4 acc[2][4];
    #pragma unroll
    for (int m = 0; m < 2; ++m)
        #pragma unroll
        for (int n = 0; n < 4; ++n)
            acc[m][n] = (f32x4){0.f, 0.f, 0.f, 0.f};

    for (int k0 = 0; k0 < EE; k0 += 64) {
        #pragma unroll
        for (int it = 0; it < 4; ++it) {
            const int tt  = tid + it * 256;
            const int row = tt >> 4, f4 = tt & 15;
            float4 v4 = *reinterpret_cast<const float4*>(x + (size_t)(i0 + row) * EE + k0 + f4 * 4);
            uint2 u;
            u.x = cvt_pk_bf16(v4.x, v4.y);
            u.y = cvt_pk_bf16(v4.z, v4.w);
            *(uint2*)(As + row * 128 + ((f4 * 8) ^ ((row & 7) << 4))) = u;
        }
        #pragma unroll
        for (int it = 0; it < 8; ++it) {
            const int tt  = tid + it * 256;
            const int row = tt >> 4, f4 = tt & 15;
            float4 v4 = *reinterpret_cast<const float4*>(W + (size_t)(f0 + row) * EE + k0 + f4 * 4);
            uint2 u;
            u.x = cvt_pk_bf16(v4.x, v4.y);
            u.y = cvt_pk_bf16(v4.z, v4.w);
            *(uint2*)(Bs + row * 128 + ((f4 * 8) ^ ((row & 7) << 4))) = u;
        }
        __syncthreads();

        #pragma unroll
        for (int ks = 0; ks < 2; ++ks) {
            short8 a[2], b[4];
            #pragma unroll
            for (int m = 0; m < 2; ++m) {
                const int row = wr * 32 + m * 16 + (lane & 15);
                a[m] = *(short8*)(As + row * 128 +
                                  ((ks * 64 + (lane >> 4) * 16) ^ ((row & 7) << 4)));
            }
            #pragma unroll
            for (int n = 0; n < 4; ++n) {
                const int row = wc * 64 + n * 16 + (lane & 15);
                b[n] = *(short8*)(Bs + row * 128 +
                                  ((ks * 64 + (lane >> 4) * 16) ^ ((row & 7) << 4)));
            }
            #pragma unroll
            for (int m = 0; m < 2; ++m)
                #pragma unroll
                for (int n = 0; n < 4; ++n)
                    acc[m][n] = __builtin_amdgcn_mfma_f32_16x16x32_bf16(a[m], b[n], acc[m][n], 0, 0, 0);
        }
        __syncthreads();
    }

    if (z == 0) {
        #pragma unroll
        for (int n = 0; n < 4; ++n) {
            const int col = f0 + wc * 64 + n * 16 + (lane & 15);
            const float bb = bias[col];
            #pragma unroll
            for (int m = 0; m < 2; ++m)
                #pragma unroll
                for (int rg = 0; rg < 4; ++rg) {
                    const int row = i0 + wr * 32 + m * 16 + (lane >> 4) * 4 + rg;
                    oq[(size_t)row * EE + col] = f2bf((acc[m][n][rg] + bb) * scale);
                }
        }
    } else if (z == 1) {
        unsigned short* ls16 = (unsigned short*)LS;
        const int b_ = i0 >> 11;
        const int c0 = i0 & 2047;
        const int h0 = f0 >> 6;
        #pragma unroll
        for (int n = 0; n < 4; ++n) {
            const int col = f0 + wc * 64 + n * 16 + (lane & 15);
            const int hl = (col >> 6) & 1;
            const int d  = col & 63;
            const float bb = bias[col];
            const int ib = (d >> 5) * 512 + ((d & 31) >> 3) * 128 + (d & 7);
            #pragma unroll
            for (int m = 0; m < 2; ++m) {
                #pragma unroll
                for (int rg = 0; rg < 4; ++rg) {
                    const int cl = wr * 32 + m * 16 + (lane >> 4) * 4 + rg;
                    ls16[(hl * 4 + (cl >> 4)) * 1024 + ib + (cl & 15) * 8] =
                        f2bf(acc[m][n][rg] + bb);
                }
            }
        }
        __syncthreads();
        #pragma unroll
        for (int it = 0; it < 4; ++it) {
            const int ci = tid + it * 256;
            const int hlfg = ci >> 7;
            const int hl = hlfg >> 2, fg = hlfg & 3;
            short8 v = *(short8*)(ls16 + ci * 8);
            *(short8*)(kswz + (size_t)(b_ * 8 + h0 + hl) * 131072 +
                       (size_t)((c0 >> 4) + fg) * 1024 + (ci & 127) * 8) = v;
        }
    } else {
        unsigned short* ls16 = (unsigned short*)LS;
        const int b_ = i0 >> 11;
        const int c0 = i0 & 2047;
        const int h0 = f0 >> 6;
        #pragma unroll
        for (int n = 0; n < 4; ++n) {
            const int col = f0 + wc * 64 + n * 16 + (lane & 15);
            const int hl = (col >> 6) & 1;
            const int d  = col & 63;
            const float bb = bias[col];
            const int ib = (d >> 4) * 512 + (d & 15) * 8;
            #pragma unroll
            for (int m = 0; m < 2; ++m) {
                #pragma unroll
                for (int rg = 0; rg < 4; ++rg) {
                    const int cl = wr * 32 + m * 16 + (lane >> 4) * 4 + rg;
                    ls16[(hl * 2 + (cl >> 5)) * 2048 + ib + ((cl >> 3) & 3) * 128 + (cl & 7)] =
                        f2h(acc[m][n][rg] + bb);
                }
            }
        }
        __syncthreads();
        #pragma unroll
        for (int it = 0; it < 4; ++it) {
            const int ci = tid + it * 256;
            const int hlch = ci >> 8;
            const int hl = hlch >> 1, ch = hlch & 1;
            short8 v = *(short8*)(ls16 + ci * 8);
            *(short8*)(vswz + (size_t)(b_ * 8 + h0 + hl) * 131072 +
                       (size_t)((c0 >> 5) + ch) * 2048 + (ci & 255) * 8) = v;
        }
    }
}

// ---------------- fused all-heads windowed attention ------------------------
// Block = (b, t). 512 threads = 8 waves; wave w owns head h = w.
// Packed b128 softmax with additive f16 mask; probs normalized in softmax.
// Vectorized attn-write: 32-float chunks, ds_read_b64 x8 per chunk.
#define RSW  296                        // u16 per P row
#define HS   2376                       // u16 per head buffer (8*296+8)
#define MV_OFF_B  (8 * HS * 2)          // 38016 (16B aligned): 288 u16 mask
#define SMEM2_BYTES (MV_OFF_B + 576 + 32)

__global__ __launch_bounds__(512, 4)
void attn_fused_kernel(const unsigned short* __restrict__ qb,
                       const unsigned short* __restrict__ kswz,
                       const unsigned short* __restrict__ vswz,
                       const unsigned char* __restrict__ kpm,
                       float* __restrict__ out,
                       float* __restrict__ attn)
{
    extern __shared__ char smem[];
    unsigned short* P16  = (unsigned short*)smem;
    unsigned short* mv16 = (unsigned short*)(smem + MV_OFF_B);

    const int bid = blockIdx.x;
    const int lin = (bid & 7) * 64 + (bid >> 3);   // XCD swizzle
    const int b   = lin >> 8;
    const int t   = lin & 255;
    const int jstart = (t - WHALF) & ~3;           // fragment-aligned window base
    const int off8   = ((t - WHALF) - jstart) * 8; // 0/8/16/24
    const int fgbase = jstart >> 1;                // key0/16
    const int kcbase = jstart >> 2;                // key0/32
    const int tid = threadIdx.x;
    const int lane = tid & 63;
    const int h    = tid >> 6;

    // ---- additive f16 mask over the aligned 288-key rectangle ----
    if (tid < 288) {
        const int j = jstart + (tid >> 3), m = tid & 7;
        const bool v = (j >= 0) && (j < TSEQ) && (j >= t - WHALF) && (j <= t + WHALF)
                       && (kpm[(b * TSEQ + j) * NAG + m] == 0);
        mv16[tid] = f2h(v ? 0.f : -30000.f);
    }

    // ---- QK^T per wave: D[8 real rows x 288]; grouped 6-frag load batches ----
    {
        const int n = lane & 7;
        const unsigned short* qbase = qb + ((size_t)(b * TSEQ + t) * NAG + n) * EE + h * HD;
        short8 aq0 = *(const short8*)(qbase + (lane >> 4) * 8);
        short8 aq1 = *(const short8*)(qbase + 32 + (lane >> 4) * 8);
        const unsigned short* kbase = kswz + (size_t)(b * 8 + h) * 131072;
        unsigned short* Ph = P16 + h * HS;
        const int r0 = (lane >> 4) * 4;
        const int cl = lane & 15;

        auto kfrag = [&](int f, int half) -> const short8* {
            int fg = fgbase + f;
            fg = (fg < 0) ? 0 : ((fg > 127) ? 127 : fg);
            return (const short8*)(kbase + fg * 1024 + half * 512 + lane * 8);
        };
        auto proc = [&](int f, short8 a0, short8 a1) {
            f32x4 a = (f32x4){0.f, 0.f, 0.f, 0.f};
            a = __builtin_amdgcn_mfma_f32_16x16x32_bf16(aq0, a0, a, 0, 0, 0);
            a = __builtin_amdgcn_mfma_f32_16x16x32_bf16(aq1, a1, a, 0, 0, 0);
            if (r0 < 8) {
                #pragma unroll
                for (int rg = 0; rg < 4; ++rg)
                    Ph[(r0 + rg) * RSW + f * 16 + cl] = f2h(a[rg]);
            }
        };

        short8 A0[6], B0[6], A1[6], B1[6];
        #pragma unroll
        for (int f = 0; f < 6; ++f) { A0[f] = *kfrag(f, 0); B0[f] = *kfrag(f, 1); }
        __builtin_amdgcn_sched_barrier(0);
        #pragma unroll
        for (int f = 0; f < 6; ++f) { A1[f] = *kfrag(6 + f, 0); B1[f] = *kfrag(6 + f, 1); }
        __builtin_amdgcn_sched_barrier(0);
        #pragma unroll
        for (int f = 0; f < 6; ++f) proc(f, A0[f], B0[f]);
        __builtin_amdgcn_sched_barrier(0);
        #pragma unroll
        for (int f = 0; f < 6; ++f) { A0[f] = *kfrag(12 + f, 0); B0[f] = *kfrag(12 + f, 1); }
        __builtin_amdgcn_sched_barrier(0);
        #pragma unroll
        for (int f = 0; f < 6; ++f) proc(6 + f, A1[f], B1[f]);
        __builtin_amdgcn_sched_barrier(0);
        #pragma unroll
        for (int f = 0; f < 6; ++f) proc(12 + f, A0[f], B0[f]);
    }
    __syncthreads();

    // ---- softmax per wave: 8 lanes/row; packed b128 chunks, normalized out ----
    {
        const int r = lane & 7, sub = lane >> 3;
        unsigned short* prow = P16 + h * HS + r * RSW;
        const bool tail = (sub < 4);

        short8 pv[5], mv[5];
        #pragma unroll
        for (int i = 0; i < 4; ++i) {
            const int c0 = sub * 8 + i * 64;        // 16B-aligned
            pv[i] = *(const short8*)(prow + c0);
            mv[i] = *(const short8*)(mv16 + c0);
        }
        if (tail) {
            const int c0 = 256 + sub * 8;
            pv[4] = *(const short8*)(prow + c0);
            mv[4] = *(const short8*)(mv16 + c0);
        }

        float lv[40];
        #pragma unroll
        for (int i = 0; i < 5; ++i)
            #pragma unroll
            for (int j = 0; j < 8; ++j) {
                if (i < 4)
                    lv[i * 8 + j] = h2f((unsigned short)pv[i][j]) + h2f((unsigned short)mv[i][j]);
                else
                    lv[i * 8 + j] = tail
                        ? h2f((unsigned short)pv[4][j]) + h2f((unsigned short)mv[4][j])
                        : -60000.f;
            }
        float mx = -INFINITY;
        #pragma unroll
        for (int k2 = 0; k2 < 40; ++k2) mx = fmaxf(mx, lv[k2]);
        mx = fmaxf(mx, __shfl_xor(mx, 8));
        mx = fmaxf(mx, __shfl_xor(mx, 16));
        mx = fmaxf(mx, __shfl_xor(mx, 32));
        float sum = 0.f;
        #pragma unroll
        for (int k2 = 0; k2 < 40; ++k2) {
            const float p = __expf(lv[k2] - mx);    // masked -> underflow to 0
            lv[k2] = p;
            sum += p;
        }
        sum += __shfl_xor(sum, 8);
        sum += __shfl_xor(sum, 16);
        sum += __shfl_xor(sum, 32);
        const float inv = 1.f / sum;

        #pragma unroll
        for (int i = 0; i < 4; ++i) {
            const int c0 = sub * 8 + i * 64;
            short8 w;
            #pragma unroll
            for (int j = 0; j < 8; ++j) w[j] = (short)f2h(lv[i * 8 + j] * inv);
            *(short8*)(prow + c0) = w;
        }
        if (tail) {
            const int c0 = 256 + sub * 8;
            short8 w;
            #pragma unroll
            for (int j = 0; j < 8; ++j) w[j] = (short)f2h(lv[32 + j] * inv);
            *(short8*)(prow + c0) = w;
        }
    }
    __syncthreads();

    // ---- PV V loads group 0 (ms 0..2), issued before the attn store loop ----
    const unsigned short* vbase = vswz + (size_t)(b * 8 + h) * 131072;
    auto vfrag = [&](int ms, int df) -> const short8* {
        int kc = kcbase + ms;
        kc = (kc < 0) ? 0 : ((kc > 63) ? 63 : kc);
        return (const short8*)(vbase + kc * 2048 + df * 512 + lane * 8);
    };
    short8 V0[3][4], V1[3][4];
    #pragma unroll
    for (int ms = 0; ms < 3; ++ms)
        #pragma unroll
        for (int df = 0; df < 4; ++df) V0[ms][df] = *vfrag(ms, df);
    __builtin_amdgcn_sched_barrier(0);

    // ---- vectorized attn write: 528 chunks of 32 floats (4 wm x 8 h) ----
    {
        float* abase = attn + (size_t)(b * TSEQ + t) * (NAG * WN * NH);
        #pragma unroll
        for (int it = 0; it < 2; ++it) {
            const int cc = tid + it * 512;
            if (cc < 528) {
                const int n   = cc / 66;
                const int rem = cc - n * 66;
                const int wm0 = rem * 4;
                float* dst = abase + ((size_t)n * WN + wm0) * NH;
                #pragma unroll
                for (int g = 0; g < 2; ++g) {
                    float pv[4][4];
                    #pragma unroll
                    for (int hb = 0; hb < 4; ++hb) {
                        const unsigned short* pp = P16 + (g * 4 + hb) * HS + n * RSW + wm0 + off8;
                        ushort4 u = *(const ushort4*)pp;    // ds_read_b64
                        pv[hb][0] = h2f(u.x); pv[hb][1] = h2f(u.y);
                        pv[hb][2] = h2f(u.z); pv[hb][3] = h2f(u.w);
                    }
                    #pragma unroll
                    for (int k = 0; k < 4; ++k) {
                        float4 v;
                        v.x = pv[0][k]; v.y = pv[1][k]; v.z = pv[2][k]; v.w = pv[3][k];
                        *(float4*)(dst + k * 8 + g * 4) = v;
                    }
                }
            }
        }
    }
    __builtin_amdgcn_sched_barrier(0);
    // no barrier: P16 is read-only from here on

    // ---- PV per wave: grouped 3x4 load batches; probs already normalized ----
    {
        const unsigned short* arow = P16 + h * HS + (lane & 7) * RSW;
        f32x4 acc[4];
        #pragma unroll
        for (int df = 0; df < 4; ++df) acc[df] = (f32x4){0.f, 0.f, 0.f, 0.f};

        auto consume = [&](int ms, short8 vv[4]) {
            short8 afr = *(const short8*)(arow + ms * 32 + (lane >> 4) * 8);
            #pragma unroll
            for (int df = 0; df < 4; ++df)
                acc[df] = __builtin_amdgcn_mfma_f32_16x16x32_f16(
                    as_f16x8(afr), as_f16x8(vv[df]), acc[df], 0, 0, 0);
        };

        #pragma unroll
        for (int ms = 0; ms < 3; ++ms)
            #pragma unroll
            for (int df = 0; df < 4; ++df) V1[ms][df] = *vfrag(3 + ms, df);
        __builtin_amdgcn_sched_barrier(0);
        #pragma unroll
        for (int ms = 0; ms < 3; ++ms) consume(ms, V0[ms]);
        __builtin_amdgcn_sched_barrier(0);
        #pragma unroll
        for (int ms = 0; ms < 3; ++ms)
            #pragma unroll
            for (int df = 0; df < 4; ++df) V0[ms][df] = *vfrag(6 + ms, df);
        __builtin_amdgcn_sched_barrier(0);
        #pragma unroll
        for (int ms = 0; ms < 3; ++ms) consume(3 + ms, V1[ms]);
        __builtin_amdgcn_sched_barrier(0);
        #pragma unroll
        for (int ms = 0; ms < 3; ++ms) consume(6 + ms, V0[ms]);

        const int r0 = (lane >> 4) * 4;
        if (r0 < 8) {
            #pragma unroll
            for (int df = 0; df < 4; ++df) {
                const int d = df * 16 + (lane & 15);
                #pragma unroll
                for (int rg = 0; rg < 4; ++rg) {
                    const int n = r0 + rg;
                    out[((size_t)(b * TSEQ + t) * NAG + n) * EE + h * HD + d] = acc[df][rg];
                }
            }
        }
    }
}

extern "C" void kernel_launch(void* const* d_in, const int* in_sizes, int n_in,
                              void* d_out, int out_size, void* d_ws, size_t ws_size,
                              hipStream_t stream) {
    const float* query = (const float*)d_in[0];
    const float* key   = (const float*)d_in[1];
    const float* value = (const float*)d_in[2];
    const unsigned char* kpm = (const unsigned char*)d_in[3];
    const float* Wq = (const float*)d_in[4];
    const float* bq = (const float*)d_in[5];
    const float* Wk = (const float*)d_in[6];
    const float* bk = (const float*)d_in[7];
    const float* Wv = (const float*)d_in[8];
    const float* bv = (const float*)d_in[9];

    float* out  = (float*)d_out;
    float* attn = out + (size_t)NBATCH * TSEQ * NAG * EE;

    unsigned short* qbf  = (unsigned short*)d_ws;              // 4 MB bf16
    unsigned short* kswz = qbf + (size_t)4096 * EE;            // 4 MB bf16 frag-order K
    unsigned short* vswz = kswz + (size_t)4096 * EE;           // 4 MB f16 frag-order V

    dim3 gp(64, 4, 3);   // BM=64 x BN=128 x {q,k,v} = 768 blocks (3/CU)
    proj_mfma_kernel<<<gp, 256, 0, stream>>>(query, key, value,
                                             Wq, Wk, Wv, bq, bk, bv,
                                             qbf, kswz, vswz);

    (void)hipFuncSetAttribute((const void*)attn_fused_kernel,
                              hipFuncAttributeMaxDynamicSharedMemorySize, SMEM2_BYTES);
    attn_fused_kernel<<<512, 512, SMEM2_BYTES, stream>>>(qbf, kswz, vswz, kpm, out, attn);
}

// Round 22
// 42.610 us; speedup vs baseline: 1.1320x; 1.1320x over previous
//
#include <hip/hip_runtime.h>
#include <hip/hip_bf16.h>

#define TSEQ 256
#define NBATCH 2
#define NAG 8
#define NH 8
#define HD 64
#define EE 512
#define WHALF 16
#define WW 33
#define WN 264   // WW*NAG

typedef __attribute__((ext_vector_type(8))) short short8;
typedef __attribute__((ext_vector_type(4))) short short4v;
typedef __attribute__((ext_vector_type(4))) float f32x4;
typedef _Float16 f16x8 __attribute__((ext_vector_type(8)));

static __device__ __forceinline__ unsigned short f2bf(float f) {
    unsigned int u = __float_as_uint(f);
    unsigned int r = (u + 0x7FFFu + ((u >> 16) & 1u)) >> 16;
    return (unsigned short)r;
}
static __device__ __forceinline__ unsigned int cvt_pk_bf16(float lo, float hi) {
    unsigned int r;
    asm("v_cvt_pk_bf16_f32 %0, %1, %2" : "=v"(r) : "v"(lo), "v"(hi));
    return r;
}
static __device__ __forceinline__ unsigned short f2h(float f) {
    _Float16 h = (_Float16)f;
    return __builtin_bit_cast(unsigned short, h);
}
static __device__ __forceinline__ float h2f(unsigned short u) {
    return (float)__builtin_bit_cast(_Float16, u);
}
static __device__ __forceinline__ f16x8 as_f16x8(short8 s) {
    return __builtin_bit_cast(f16x8, s);
}

// ---------------- fused QKV projection GEMM (bf16 MFMA) -----------------
// BM=64, BN=128, BK=64, 4 waves. 768 blocks.
__global__ __launch_bounds__(256)
void proj_mfma_kernel(const float* __restrict__ xq, const float* __restrict__ xk,
                      const float* __restrict__ xv,
                      const float* __restrict__ Wq, const float* __restrict__ Wk,
                      const float* __restrict__ Wv,
                      const float* __restrict__ bq, const float* __restrict__ bk,
                      const float* __restrict__ bv,
                      unsigned short* __restrict__ oq,
                      unsigned short* __restrict__ kswz,
                      unsigned short* __restrict__ vswz)
{
    __shared__ __align__(16) char LS[24576];
    char* As = LS;
    char* Bs = LS + 8192;

    const float* x; const float* W; const float* bias; float scale;
    const int z = blockIdx.z;
    if (z == 0)      { x = xq; W = Wq; bias = bq; scale = 0.125f; }
    else if (z == 1) { x = xk; W = Wk; bias = bk; scale = 1.0f; }
    else             { x = xv; W = Wv; bias = bv; scale = 1.0f; }

    const int tid  = threadIdx.x;
    const int lane = tid & 63;
    const int wid  = tid >> 6;
    const int i0 = blockIdx.x * 64;
    const int f0 = blockIdx.y * 128;
    const int wr = wid >> 1, wc = wid & 1;

    f32x4 acc[2][4];
    #pragma unroll
    for (int m = 0; m < 2; ++m)
        #pragma unroll
        for (int n = 0; n < 4; ++n)
            acc[m][n] = (f32x4){0.f, 0.f, 0.f, 0.f};

    for (int k0 = 0; k0 < EE; k0 += 64) {
        #pragma unroll
        for (int it = 0; it < 4; ++it) {
            const int tt  = tid + it * 256;
            const int row = tt >> 4, f4 = tt & 15;
            float4 v4 = *reinterpret_cast<const float4*>(x + (size_t)(i0 + row) * EE + k0 + f4 * 4);
            uint2 u;
            u.x = cvt_pk_bf16(v4.x, v4.y);
            u.y = cvt_pk_bf16(v4.z, v4.w);
            *(uint2*)(As + row * 128 + ((f4 * 8) ^ ((row & 7) << 4))) = u;
        }
        #pragma unroll
        for (int it = 0; it < 8; ++it) {
            const int tt  = tid + it * 256;
            const int row = tt >> 4, f4 = tt & 15;
            float4 v4 = *reinterpret_cast<const float4*>(W + (size_t)(f0 + row) * EE + k0 + f4 * 4);
            uint2 u;
            u.x = cvt_pk_bf16(v4.x, v4.y);
            u.y = cvt_pk_bf16(v4.z, v4.w);
            *(uint2*)(Bs + row * 128 + ((f4 * 8) ^ ((row & 7) << 4))) = u;
        }
        __syncthreads();

        #pragma unroll
        for (int ks = 0; ks < 2; ++ks) {
            short8 a[2], b[4];
            #pragma unroll
            for (int m = 0; m < 2; ++m) {
                const int row = wr * 32 + m * 16 + (lane & 15);
                a[m] = *(short8*)(As + row * 128 +
                                  ((ks * 64 + (lane >> 4) * 16) ^ ((row & 7) << 4)));
            }
            #pragma unroll
            for (int n = 0; n < 4; ++n) {
                const int row = wc * 64 + n * 16 + (lane & 15);
                b[n] = *(short8*)(Bs + row * 128 +
                                  ((ks * 64 + (lane >> 4) * 16) ^ ((row & 7) << 4)));
            }
            #pragma unroll
            for (int m = 0; m < 2; ++m)
                #pragma unroll
                for (int n = 0; n < 4; ++n)
                    acc[m][n] = __builtin_amdgcn_mfma_f32_16x16x32_bf16(a[m], b[n], acc[m][n], 0, 0, 0);
        }
        __syncthreads();
    }

    if (z == 0) {
        #pragma unroll
        for (int n = 0; n < 4; ++n) {
            const int col = f0 + wc * 64 + n * 16 + (lane & 15);
            const float bb = bias[col];
            #pragma unroll
            for (int m = 0; m < 2; ++m)
                #pragma unroll
                for (int rg = 0; rg < 4; ++rg) {
                    const int row = i0 + wr * 32 + m * 16 + (lane >> 4) * 4 + rg;
                    oq[(size_t)row * EE + col] = f2bf((acc[m][n][rg] + bb) * scale);
                }
        }
    } else if (z == 1) {
        unsigned short* ls16 = (unsigned short*)LS;
        const int b_ = i0 >> 11;
        const int c0 = i0 & 2047;
        const int h0 = f0 >> 6;
        #pragma unroll
        for (int n = 0; n < 4; ++n) {
            const int col = f0 + wc * 64 + n * 16 + (lane & 15);
            const int hl = (col >> 6) & 1;
            const int d  = col & 63;
            const float bb = bias[col];
            const int ib = (d >> 5) * 512 + ((d & 31) >> 3) * 128 + (d & 7);
            #pragma unroll
            for (int m = 0; m < 2; ++m) {
                #pragma unroll
                for (int rg = 0; rg < 4; ++rg) {
                    const int cl = wr * 32 + m * 16 + (lane >> 4) * 4 + rg;
                    ls16[(hl * 4 + (cl >> 4)) * 1024 + ib + (cl & 15) * 8] =
                        f2bf(acc[m][n][rg] + bb);
                }
            }
        }
        __syncthreads();
        #pragma unroll
        for (int it = 0; it < 4; ++it) {
            const int ci = tid + it * 256;
            const int hlfg = ci >> 7;
            const int hl = hlfg >> 2, fg = hlfg & 3;
            short8 v = *(short8*)(ls16 + ci * 8);
            *(short8*)(kswz + (size_t)(b_ * 8 + h0 + hl) * 131072 +
                       (size_t)((c0 >> 4) + fg) * 1024 + (ci & 127) * 8) = v;
        }
    } else {
        unsigned short* ls16 = (unsigned short*)LS;
        const int b_ = i0 >> 11;
        const int c0 = i0 & 2047;
        const int h0 = f0 >> 6;
        #pragma unroll
        for (int n = 0; n < 4; ++n) {
            const int col = f0 + wc * 64 + n * 16 + (lane & 15);
            const int hl = (col >> 6) & 1;
            const int d  = col & 63;
            const float bb = bias[col];
            const int ib = (d >> 4) * 512 + (d & 15) * 8;
            #pragma unroll
            for (int m = 0; m < 2; ++m) {
                #pragma unroll
                for (int rg = 0; rg < 4; ++rg) {
                    const int cl = wr * 32 + m * 16 + (lane >> 4) * 4 + rg;
                    ls16[(hl * 2 + (cl >> 5)) * 2048 + ib + ((cl >> 3) & 3) * 128 + (cl & 7)] =
                        f2h(acc[m][n][rg] + bb);
                }
            }
        }
        __syncthreads();
        #pragma unroll
        for (int it = 0; it < 4; ++it) {
            const int ci = tid + it * 256;
            const int hlch = ci >> 8;
            const int hl = hlch >> 1, ch = hlch & 1;
            short8 v = *(short8*)(ls16 + ci * 8);
            *(short8*)(vswz + (size_t)(b_ * 8 + h0 + hl) * 131072 +
                       (size_t)((c0 >> 5) + ch) * 2048 + (ci & 255) * 8) = v;
        }
    }
}

// ---------------- fused all-heads windowed attention ------------------------
// Block = (b, t). 512 threads = 8 waves; wave w owns head h = w.
// Packed b128 softmax with additive f16 mask; probs normalized in softmax.
#define RSW  296                        // u16 per P row
#define HS   2376                       // u16 per head buffer (8*296+8)
#define MV_OFF_B  (8 * HS * 2)          // 38016 (16B aligned): 288 u16 mask
#define SMEM2_BYTES (MV_OFF_B + 576 + 32)

__global__ __launch_bounds__(512, 4)
void attn_fused_kernel(const unsigned short* __restrict__ qb,
                       const unsigned short* __restrict__ kswz,
                       const unsigned short* __restrict__ vswz,
                       const unsigned char* __restrict__ kpm,
                       float* __restrict__ out,
                       float* __restrict__ attn)
{
    extern __shared__ char smem[];
    unsigned short* P16  = (unsigned short*)smem;
    unsigned short* mv16 = (unsigned short*)(smem + MV_OFF_B);

    const int bid = blockIdx.x;
    const int lin = (bid & 7) * 64 + (bid >> 3);   // XCD swizzle
    const int b   = lin >> 8;
    const int t   = lin & 255;
    const int jstart = (t - WHALF) & ~3;           // fragment-aligned window base
    const int off8   = ((t - WHALF) - jstart) * 8; // 0/8/16/24
    const int fgbase = jstart >> 1;                // key0/16
    const int kcbase = jstart >> 2;                // key0/32
    const int tid = threadIdx.x;
    const int lane = tid & 63;
    const int h    = tid >> 6;

    // ---- additive f16 mask over the aligned 288-key rectangle ----
    if (tid < 288) {
        const int j = jstart + (tid >> 3), m = tid & 7;
        const bool v = (j >= 0) && (j < TSEQ) && (j >= t - WHALF) && (j <= t + WHALF)
                       && (kpm[(b * TSEQ + j) * NAG + m] == 0);
        mv16[tid] = f2h(v ? 0.f : -30000.f);
    }

    // ---- QK^T per wave: D[8 real rows x 288]; grouped 6-frag load batches ----
    {
        const int n = lane & 7;
        const unsigned short* qbase = qb + ((size_t)(b * TSEQ + t) * NAG + n) * EE + h * HD;
        short8 aq0 = *(const short8*)(qbase + (lane >> 4) * 8);
        short8 aq1 = *(const short8*)(qbase + 32 + (lane >> 4) * 8);
        const unsigned short* kbase = kswz + (size_t)(b * 8 + h) * 131072;
        unsigned short* Ph = P16 + h * HS;
        const int r0 = (lane >> 4) * 4;
        const int cl = lane & 15;

        auto kfrag = [&](int f, int half) -> const short8* {
            int fg = fgbase + f;
            fg = (fg < 0) ? 0 : ((fg > 127) ? 127 : fg);
            return (const short8*)(kbase + fg * 1024 + half * 512 + lane * 8);
        };
        auto proc = [&](int f, short8 a0, short8 a1) {
            f32x4 a = (f32x4){0.f, 0.f, 0.f, 0.f};
            a = __builtin_amdgcn_mfma_f32_16x16x32_bf16(aq0, a0, a, 0, 0, 0);
            a = __builtin_amdgcn_mfma_f32_16x16x32_bf16(aq1, a1, a, 0, 0, 0);
            if (r0 < 8) {
                #pragma unroll
                for (int rg = 0; rg < 4; ++rg)
                    Ph[(r0 + rg) * RSW + f * 16 + cl] = f2h(a[rg]);
            }
        };

        short8 A0[6], B0[6], A1[6], B1[6];
        #pragma unroll
        for (int f = 0; f < 6; ++f) { A0[f] = *kfrag(f, 0); B0[f] = *kfrag(f, 1); }
        __builtin_amdgcn_sched_barrier(0);
        #pragma unroll
        for (int f = 0; f < 6; ++f) { A1[f] = *kfrag(6 + f, 0); B1[f] = *kfrag(6 + f, 1); }
        __builtin_amdgcn_sched_barrier(0);
        #pragma unroll
        for (int f = 0; f < 6; ++f) proc(f, A0[f], B0[f]);
        __builtin_amdgcn_sched_barrier(0);
        #pragma unroll
        for (int f = 0; f < 6; ++f) { A0[f] = *kfrag(12 + f, 0); B0[f] = *kfrag(12 + f, 1); }
        __builtin_amdgcn_sched_barrier(0);
        #pragma unroll
        for (int f = 0; f < 6; ++f) proc(6 + f, A1[f], B1[f]);
        __builtin_amdgcn_sched_barrier(0);
        #pragma unroll
        for (int f = 0; f < 6; ++f) proc(12 + f, A0[f], B0[f]);
    }
    __syncthreads();

    // ---- softmax per wave: 8 lanes/row; packed b128 chunks, normalized out ----
    {
        const int r = lane & 7, sub = lane >> 3;
        unsigned short* prow = P16 + h * HS + r * RSW;
        const bool tail = (sub < 4);

        short8 pv[5], mv[5];
        #pragma unroll
        for (int i = 0; i < 4; ++i) {
            const int c0 = sub * 8 + i * 64;        // 16B-aligned
            pv[i] = *(const short8*)(prow + c0);
            mv[i] = *(const short8*)(mv16 + c0);
        }
        if (tail) {
            const int c0 = 256 + sub * 8;
            pv[4] = *(const short8*)(prow + c0);
            mv[4] = *(const short8*)(mv16 + c0);
        }

        float lv[40];
        #pragma unroll
        for (int i = 0; i < 5; ++i)
            #pragma unroll
            for (int j = 0; j < 8; ++j) {
                if (i < 4)
                    lv[i * 8 + j] = h2f((unsigned short)pv[i][j]) + h2f((unsigned short)mv[i][j]);
                else
                    lv[i * 8 + j] = tail
                        ? h2f((unsigned short)pv[4][j]) + h2f((unsigned short)mv[4][j])
                        : -60000.f;
            }
        float mx = -INFINITY;
        #pragma unroll
        for (int k2 = 0; k2 < 40; ++k2) mx = fmaxf(mx, lv[k2]);
        mx = fmaxf(mx, __shfl_xor(mx, 8));
        mx = fmaxf(mx, __shfl_xor(mx, 16));
        mx = fmaxf(mx, __shfl_xor(mx, 32));
        float sum = 0.f;
        #pragma unroll
        for (int k2 = 0; k2 < 40; ++k2) {
            const float p = __expf(lv[k2] - mx);    // masked -> underflow to 0
            lv[k2] = p;
            sum += p;
        }
        sum += __shfl_xor(sum, 8);
        sum += __shfl_xor(sum, 16);
        sum += __shfl_xor(sum, 32);
        const float inv = 1.f / sum;

        #pragma unroll
        for (int i = 0; i < 4; ++i) {
            const int c0 = sub * 8 + i * 64;
            short8 w;
            #pragma unroll
            for (int j = 0; j < 8; ++j) w[j] = (short)f2h(lv[i * 8 + j] * inv);
            *(short8*)(prow + c0) = w;
        }
        if (tail) {
            const int c0 = 256 + sub * 8;
            short8 w;
            #pragma unroll
            for (int j = 0; j < 8; ++j) w[j] = (short)f2h(lv[32 + j] * inv);
            *(short8*)(prow + c0) = w;
        }
    }
    __syncthreads();

    // ---- PV V loads group 0 (ms 0..2), issued before the attn store loop ----
    const unsigned short* vbase = vswz + (size_t)(b * 8 + h) * 131072;
    auto vfrag = [&](int ms, int df) -> const short8* {
        int kc = kcbase + ms;
        kc = (kc < 0) ? 0 : ((kc > 63) ? 63 : kc);
        return (const short8*)(vbase + kc * 2048 + df * 512 + lane * 8);
    };
    short8 V0[3][4], V1[3][4];
    #pragma unroll
    for (int ms = 0; ms < 3; ++ms)
        #pragma unroll
        for (int df = 0; df < 4; ++df) V0[ms][df] = *vfrag(ms, df);
    __builtin_amdgcn_sched_barrier(0);

    // ---- cooperative coalesced attn write: pure gather (probs pre-normalized) ----
    {
        float* abase = attn + (size_t)(b * TSEQ + t) * (NAG * WN * NH);
        #pragma unroll 3
        for (int q4 = tid; q4 < 4224; q4 += 512) {
            const int hh = q4 & 1;
            const int rw = q4 >> 1;                    // n*264 + wm
            const int n  = rw / WN;
            const int wm = rw - n * WN;
            const int h0 = hh * 4;
            const unsigned short* pp = P16 + h0 * HS + n * RSW + wm + off8;
            float4 v;
            v.x = h2f(pp[0]);
            v.y = h2f(pp[HS]);
            v.z = h2f(pp[2 * HS]);
            v.w = h2f(pp[3 * HS]);
            *(float4*)(abase + (size_t)q4 * 4) = v;
        }
    }
    __builtin_amdgcn_sched_barrier(0);
    // no barrier: P16 is read-only from here on

    // ---- PV per wave: grouped 3x4 load batches; probs already normalized ----
    {
        const unsigned short* arow = P16 + h * HS + (lane & 7) * RSW;
        f32x4 acc[4];
        #pragma unroll
        for (int df = 0; df < 4; ++df) acc[df] = (f32x4){0.f, 0.f, 0.f, 0.f};

        auto consume = [&](int ms, short8 vv[4]) {
            short8 afr = *(const short8*)(arow + ms * 32 + (lane >> 4) * 8);
            #pragma unroll
            for (int df = 0; df < 4; ++df)
                acc[df] = __builtin_amdgcn_mfma_f32_16x16x32_f16(
                    as_f16x8(afr), as_f16x8(vv[df]), acc[df], 0, 0, 0);
        };

        #pragma unroll
        for (int ms = 0; ms < 3; ++ms)
            #pragma unroll
            for (int df = 0; df < 4; ++df) V1[ms][df] = *vfrag(3 + ms, df);
        __builtin_amdgcn_sched_barrier(0);
        #pragma unroll
        for (int ms = 0; ms < 3; ++ms) consume(ms, V0[ms]);
        __builtin_amdgcn_sched_barrier(0);
        #pragma unroll
        for (int ms = 0; ms < 3; ++ms)
            #pragma unroll
            for (int df = 0; df < 4; ++df) V0[ms][df] = *vfrag(6 + ms, df);
        __builtin_amdgcn_sched_barrier(0);
        #pragma unroll
        for (int ms = 0; ms < 3; ++ms) consume(3 + ms, V1[ms]);
        __builtin_amdgcn_sched_barrier(0);
        #pragma unroll
        for (int ms = 0; ms < 3; ++ms) consume(6 + ms, V0[ms]);

        const int r0 = (lane >> 4) * 4;
        if (r0 < 8) {
            #pragma unroll
            for (int df = 0; df < 4; ++df) {
                const int d = df * 16 + (lane & 15);
                #pragma unroll
                for (int rg = 0; rg < 4; ++rg) {
                    const int n = r0 + rg;
                    out[((size_t)(b * TSEQ + t) * NAG + n) * EE + h * HD + d] = acc[df][rg];
                }
            }
        }
    }
}

extern "C" void kernel_launch(void* const* d_in, const int* in_sizes, int n_in,
                              void* d_out, int out_size, void* d_ws, size_t ws_size,
                              hipStream_t stream) {
    const float* query = (const float*)d_in[0];
    const float* key   = (const float*)d_in[1];
    const float* value = (const float*)d_in[2];
    const unsigned char* kpm = (const unsigned char*)d_in[3];
    const float* Wq = (const float*)d_in[4];
    const float* bq = (const float*)d_in[5];
    const float* Wk = (const float*)d_in[6];
    const float* bk = (const float*)d_in[7];
    const float* Wv = (const float*)d_in[8];
    const float* bv = (const float*)d_in[9];

    float* out  = (float*)d_out;
    float* attn = out + (size_t)NBATCH * TSEQ * NAG * EE;

    unsigned short* qbf  = (unsigned short*)d_ws;              // 4 MB bf16
    unsigned short* kswz = qbf + (size_t)4096 * EE;            // 4 MB bf16 frag-order K
    unsigned short* vswz = kswz + (size_t)4096 * EE;           // 4 MB f16 frag-order V

    dim3 gp(64, 4, 3);   // BM=64 x BN=128 x {q,k,v} = 768 blocks (3/CU)
    proj_mfma_kernel<<<gp, 256, 0, stream>>>(query, key, value,
                                             Wq, Wk, Wv, bq, bk, bv,
                                             qbf, kswz, vswz);

    (void)hipFuncSetAttribute((const void*)attn_fused_kernel,
                              hipFuncAttributeMaxDynamicSharedMemorySize, SMEM2_BYTES);
    attn_fused_kernel<<<512, 512, SMEM2_BYTES, stream>>>(qbf, kswz, vswz, kpm, out, attn);
}